// Round 1
// 591.123 us; speedup vs baseline: 1.0058x; 1.0058x over previous
//
#include <hip/hip_runtime.h>
#include <cfloat>

// Problem constants (from reference): FACTOR=3, IPS=64, BP=5
//   CENTER=72, LO=57, HI=87(excl), NEW_CENTER=57, ALIGNED_LEN=192, L=220
#define LCOLS        220
#define WIN_LO       57
#define WIN_HI       86     // inclusive
#define ALIGNED_LEN_ 192
#define MAX_START    28     // L - ALIGNED_LEN
#define IPS_         64
#define TILE_ROWS    32
#define TILE_WORDS   (TILE_ROWS * LCOLS)   // 7040 floats = 28160 B

__device__ __forceinline__ void async_copy16(const float* gsrc, float* ldst) {
    __builtin_amdgcn_global_load_lds(
        (const __attribute__((address_space(1))) void*)gsrc,
        (__attribute__((address_space(3))) void*)ldst, 16, 0, 0);
}

// Block = 128 (2 waves), tile = 32 rows. LDS 28.2 KB -> 5 blocks/CU.
// Mapping: thread t -> row r = t>>2, quarter q = t&3.
// All per-row reductions via __shfl_xor within the 4-lane group:
// exactly ONE __syncthreads per tile (after staging).
__global__ __launch_bounds__(128) void peak_align_tile(
    const float* __restrict__ in,
    float* __restrict__ out_spikes,   // [K, 64]
    float* __restrict__ out_mask,     // [K]
    int K)
{
    // +4 floats pad: quarter 3 reads f4 j=55 (cols 220..223); those cols are
    // always outside [s, s+192) (s<=28 -> s+192<=220) so garbage is masked.
    __shared__ __align__(16) float tile[TILE_WORDS + 4];

    const int t    = threadIdx.x;
    const int lane = t & 63;
    const int wave = t >> 6;                         // 0 or 1
    const long long base = (long long)blockIdx.x * TILE_ROWS;
    const int rows = (int)(((long long)K - base) < TILE_ROWS ? (K - base) : TILE_ROWS);
    const float* src = in + base * LCOLS;

    // ---- Phase 1: stage rows*880 B contiguous global -> LDS (2 waves) ----
    const int bytes = rows * (LCOLS * 4);            // 28160 for full tile
    const int nfull = bytes >> 10;                   // 27 full 1 KB chunks
    for (int it = wave; it < nfull; it += 2) {
        async_copy16(src + (it << 8) + lane * 4, &tile[it << 8]);
    }
    const int rem = bytes - (nfull << 10);           // 512 B tail (full tile)
    if (t * 16 < rem) {
        const float4 v = *(const float4*)(src + (nfull << 8) + t * 4);
        *(float4*)&tile[(nfull << 8) + t * 4] = v;
    }
    __syncthreads();                                 // the ONLY barrier

    const int r = t >> 2;                            // row 0..31
    const int q = t & 3;                             // quarter 0..3
    const bool live = (r < rows);
    const float* row = &tile[r * LCOLS];

    // ---- Phase 2a: window argmax cols [57,86]; thread q covers f4 {14+2q, 15+2q} ----
    float bv = -FLT_MAX; int bi = 0x7fffffff;
    if (live) {
        #pragma unroll
        for (int jj = 0; jj < 2; ++jj) {
            const int j = 14 + 2 * q + jj;
            const float4 v = *(const float4*)(row + (j << 2));
            const float qq[4] = {v.x, v.y, v.z, v.w};
            #pragma unroll
            for (int k = 0; k < 4; ++k) {
                const int c = (j << 2) + k;
                if (c >= WIN_LO && c <= WIN_HI && qq[k] > bv) { bv = qq[k]; bi = c; }
            }
        }
    }
    // butterfly argmax (first occurrence) across the 4-lane group
    #pragma unroll
    for (int m = 1; m <= 2; m <<= 1) {
        const float ov = __shfl_xor(bv, m);
        const int   oi = __shfl_xor(bi, m);
        if (ov > bv || (ov == bv && oi < bi)) { bv = ov; bi = oi; }
    }
    const int  start = bi - WIN_LO;                  // [0, 29] (live rows)
    const bool in_b  = (start <= MAX_START);
    const int  s     = in_b ? start : MAX_START;

    // ---- Phase 2b: aligned argmax over [s, s+192); thread q scans f4 [14q, 14q+14) ----
    float av = -FLT_MAX; int ai = 0x7fffffff;
    if (live) {
        const int jlo = 14 * q;
        #pragma unroll
        for (int jj = 0; jj < 14; ++jj) {
            const int j = jlo + jj;
            const float4 v = *(const float4*)(row + (j << 2));
            const float qq[4] = {v.x, v.y, v.z, v.w};
            #pragma unroll
            for (int k = 0; k < 4; ++k) {
                const int c = (j << 2) + k;
                const bool inr = (unsigned)(c - s) < (unsigned)ALIGNED_LEN_;
                if (inr && qq[k] > av) { av = qq[k]; ai = c; }
            }
        }
    }
    #pragma unroll
    for (int m = 1; m <= 2; m <<= 1) {
        const float ov = __shfl_xor(av, m);
        const int   oi = __shfl_xor(ai, m);
        if (ov > av || (ov == av && oi < ai)) { av = ov; ai = oi; }
    }
    // aligned argmax at NEW_CENTER  <=>  global first-occurrence max at col s+57
    const bool valid = in_b && (ai == s + WIN_LO);

    if (live && q == 0) {
        out_mask[base + r] = valid ? 0.0f : 1.0f;    // removed_mask = ~valid
    }

    // ---- Phase 3: gather + store; thread q writes out cols [16q, 16q+16) ----
    if (live) {
        const int cbase = s + 3 * (q << 4);          // s + 48q  (<= 28+144)
        float4* dst = (float4*)&out_spikes[(base + r) * IPS_ + (q << 4)];
        #pragma unroll
        for (int ii = 0; ii < 4; ++ii) {
            float vv[4];
            #pragma unroll
            for (int k = 0; k < 4; ++k) {
                const float g = row[cbase + 3 * ((ii << 2) + k)];
                vv[k] = valid ? g : 0.0f;
            }
            dst[ii] = make_float4(vv[0], vv[1], vv[2], vv[3]);
        }
    }
}

extern "C" void kernel_launch(void* const* d_in, const int* in_sizes, int n_in,
                              void* d_out, int out_size, void* d_ws, size_t ws_size,
                              hipStream_t stream) {
    const float* in = (const float*)d_in[0];
    const int K = in_sizes[0] / LCOLS;               // 500000

    float* out_spikes = (float*)d_out;
    float* out_mask   = out_spikes + (long long)K * IPS_;

    const int grid = (K + TILE_ROWS - 1) / TILE_ROWS;   // 15625
    hipLaunchKernelGGL(peak_align_tile, dim3(grid), dim3(128), 0, stream,
                       in, out_spikes, out_mask, K);
}